// Round 3
// baseline (4573.994 us; speedup 1.0000x reference)
//
#include <hip/hip_runtime.h>

// BERT classifier fwd, MI355X. Round 2: round-1 structure (ws 151 MB, fused
// accum epilogues) + inline-asm MFMA (proven-compiling in this env).
// x kept f32 (xf) + bf16 shadow (xb). Wo/FFN2 GEMMs accumulate into xf.
// Weights converted f32->bf16 on the fly in GEMM B-staging. FFN chunked F/2.

#define E_DIM 768
#define F_DIM 3072
#define L_NUM 4
#define S_LEN 512
#define NTOK  (S_LEN * 32)   // 16384

typedef float f32x4 __attribute__((ext_vector_type(4)));
typedef unsigned int u32x4 __attribute__((ext_vector_type(4)));

__device__ __forceinline__ float bf2f(unsigned int bits) {
    return __uint_as_float(bits << 16);
}
__device__ __forceinline__ unsigned short f2bf(float f) {
    unsigned int x = __float_as_uint(f);
    return (unsigned short)((x + 0x7fffu + ((x >> 16) & 1u)) >> 16);
}

// ---------------------------------------------------------------- embedding
__global__ __launch_bounds__(256)
void embed_k(const int* __restrict__ ids, const float* __restrict__ tok,
             const float* __restrict__ pos, float* __restrict__ xf,
             unsigned short* __restrict__ xb)
{
    const int row = blockIdx.x;            // token = s*32 + b
    const int s = row >> 5;
    const int id = ids[row];
    const size_t rb = (size_t)row * E_DIM;
    for (int e = threadIdx.x; e < E_DIM; e += 256) {
        float v = tok[(size_t)id * E_DIM + e] + pos[(size_t)s * E_DIM + e];
        xf[rb + e] = v;
        xb[rb + e] = f2bf(v);
    }
}

// ---------------------------------------------------------------- GEMM
// C[M,Ntile] = A[M,K](bf16) @ B[K,N](f32, cvt on the fly) + bias
// 64x64x64 tile, 4 waves, v_mfma_f32_16x16x32_bf16 (inline asm).
// ACCUM: C(f32) += acc + bias.  OUT_BF16: write bf16 else f32.
#define BM 64
#define BN 64
#define BKT 64
#define LDT 80   // shorts; row stride 160B: 16B-aligned b128 frag reads

template<int OUT_BF16, int RELU, int ACCUM>
__global__ __launch_bounds__(256)
void gemm_k(const unsigned short* __restrict__ A, const float* __restrict__ B,
            const float* __restrict__ bias, void* __restrict__ Cout,
            int lda, int ldb, int ldc, int K)
{
    __shared__ unsigned short As[BM * LDT];
    __shared__ unsigned short Bs[BN * LDT];
    const int t = threadIdx.x;
    const int i0 = blockIdx.x * BM, j0 = blockIdx.y * BN;
    const int lane = t & 63, wave = t >> 6;
    const int wm = wave >> 1, wn = wave & 1;
    const int lr = lane & 15, lg = lane >> 4;

    f32x4 acc[2][2];
    #pragma unroll
    for (int m = 0; m < 2; m++)
        #pragma unroll
        for (int n = 0; n < 2; n++) acc[m][n] = (f32x4)0.0f;

    const int ar  = t >> 3;          // 0..31 (row, +32 pair)
    const int ac8 = (t & 7) * 8;     // 16B chunk col
    const int bkk = t >> 3;          // 0..31 (k, +32 pair)
    const int bj8 = (t & 7) * 8;     // 8-col group

    for (int k0 = 0; k0 < K; k0 += BKT) {
        __syncthreads();
        // A tile [64][64] bf16 row-major (padded LDT)
        u32x4 v0 = *(const u32x4*)(A + (size_t)(i0 + ar)      * lda + k0 + ac8);
        u32x4 v1 = *(const u32x4*)(A + (size_t)(i0 + ar + 32) * lda + k0 + ac8);
        *(u32x4*)(&As[ar        * LDT + ac8]) = v0;
        *(u32x4*)(&As[(ar + 32) * LDT + ac8]) = v1;
        // B tile transposed + f32->bf16: Bs[j][kk] = bf16(B[k0+kk][j0+j])
        const float* Bp0 = B + (size_t)(k0 + bkk)      * ldb + j0 + bj8;
        const float* Bp1 = B + (size_t)(k0 + bkk + 32) * ldb + j0 + bj8;
        f32x4 w0 = *(const f32x4*)(Bp0);
        f32x4 w1 = *(const f32x4*)(Bp0 + 4);
        f32x4 w2 = *(const f32x4*)(Bp1);
        f32x4 w3 = *(const f32x4*)(Bp1 + 4);
        #pragma unroll
        for (int e = 0; e < 4; e++) {
            Bs[(bj8 + e)     * LDT + bkk]      = f2bf(w0[e]);
            Bs[(bj8 + 4 + e) * LDT + bkk]      = f2bf(w1[e]);
            Bs[(bj8 + e)     * LDT + bkk + 32] = f2bf(w2[e]);
            Bs[(bj8 + 4 + e) * LDT + bkk + 32] = f2bf(w3[e]);
        }
        __syncthreads();
        #pragma unroll
        for (int kk = 0; kk < BKT; kk += 32) {
            u32x4 a0 = *(const u32x4*)(&As[(wm * 32 +      lr) * LDT + kk + lg * 8]);
            u32x4 a1 = *(const u32x4*)(&As[(wm * 32 + 16 + lr) * LDT + kk + lg * 8]);
            u32x4 b0 = *(const u32x4*)(&Bs[(wn * 32 +      lr) * LDT + kk + lg * 8]);
            u32x4 b1 = *(const u32x4*)(&Bs[(wn * 32 + 16 + lr) * LDT + kk + lg * 8]);
            asm volatile("v_mfma_f32_16x16x32_bf16 %0, %1, %2, %0" : "+v"(acc[0][0]) : "v"(a0), "v"(b0));
            asm volatile("v_mfma_f32_16x16x32_bf16 %0, %1, %2, %0" : "+v"(acc[0][1]) : "v"(a0), "v"(b1));
            asm volatile("v_mfma_f32_16x16x32_bf16 %0, %1, %2, %0" : "+v"(acc[1][0]) : "v"(a1), "v"(b0));
            asm volatile("v_mfma_f32_16x16x32_bf16 %0, %1, %2, %0" : "+v"(acc[1][1]) : "v"(a1), "v"(b1));
        }
    }
    // D-read hazard insurance before VALU epilogue (inline asm hides MFMA
    // from the compiler's hazard recognizer).
    asm volatile("s_nop 7\n\ts_nop 7");
    // epilogue: C/D layout col=lane&15, row=(lane>>4)*4+reg  [m89-verified]
    #pragma unroll
    for (int n = 0; n < 2; n++) {
        const int col = j0 + wn * 32 + n * 16 + lr;
        const float bv = bias ? bias[col] : 0.0f;
        #pragma unroll
        for (int m = 0; m < 2; m++) {
            #pragma unroll
            for (int j = 0; j < 4; j++) {
                const int row = i0 + wm * 32 + m * 16 + lg * 4 + j;
                const size_t idx = (size_t)row * ldc + col;
                float v = acc[m][n][j] + bv;
                if (RELU) v = fmaxf(v, 0.0f);
                if (ACCUM)         ((float*)Cout)[idx] += v;
                else if (OUT_BF16) ((unsigned short*)Cout)[idx] = f2bf(v);
                else               ((float*)Cout)[idx] = v;
            }
        }
    }
}

// ---------------------------------------------------------------- attention
// Per s: scores[b,c] over BATCH (faithful to ref bug), softmax, PV.
// aob may alias Qb: Q fully consumed before the barrier preceding AO writes.
__global__ __launch_bounds__(1024)
void attn_k(const unsigned short* __restrict__ Qb, const unsigned short* __restrict__ Kb,
            const unsigned short* __restrict__ Vb, unsigned short* __restrict__ aob)
{
    __shared__ unsigned short Ks[32 * 776];   // +8 pad
    __shared__ float attn_s[32 * 33];
    __shared__ float attn_t[32 * 36];         // transposed [c][q], rows 144B (16B mult)
    const int s = blockIdx.x;
    const int t = threadIdx.x;
    const int base = s * 32;

    for (int ch = t; ch < 32 * 96; ch += 1024) {
        const int r = ch / 96, e = (ch % 96) * 8;
        *(u32x4*)(&Ks[r * 776 + e]) = *(const u32x4*)(Kb + (size_t)(base + r) * E_DIM + e);
    }
    __syncthreads();
    {   // scores: thread (q,c); Q row from global (L1 broadcast), K from LDS
        const int q = t >> 5, c = t & 31;
        const unsigned short* Qg = Qb + (size_t)(base + q) * E_DIM;
        float acc = 0.f;
        for (int e = 0; e < E_DIM; e += 8) {
            u32x4 qv = *(const u32x4*)(Qg + e);
            u32x4 kv = *(const u32x4*)(&Ks[c * 776 + e]);
            #pragma unroll
            for (int w = 0; w < 4; w++) {
                acc += bf2f(qv[w] & 0xffffu) * bf2f(kv[w] & 0xffffu);
                acc += bf2f(qv[w] >> 16)     * bf2f(kv[w] >> 16);
            }
        }
        attn_s[q * 33 + c] = acc * 0.036084391824351615f;  // 1/sqrt(768)
    }
    __syncthreads();
    if (t < 32) {   // softmax row t
        float mx = -1e30f;
        #pragma unroll
        for (int c = 0; c < 32; c++) mx = fmaxf(mx, attn_s[t * 33 + c]);
        float sum = 0.f;
        #pragma unroll
        for (int c = 0; c < 32; c++) sum += expf(attn_s[t * 33 + c] - mx);
        const float r = 1.0f / sum;
        #pragma unroll
        for (int c = 0; c < 32; c++)
            attn_t[c * 36 + t] = expf(attn_s[t * 33 + c] - mx) * r;
    }
    __syncthreads();
    if (t < E_DIM) {   // PV: thread owns column e=t
        float o[32];
        #pragma unroll
        for (int q = 0; q < 32; q++) o[q] = 0.f;
        for (int c = 0; c < 32; c++) {
            const float vv = bf2f(Vb[(size_t)(base + c) * E_DIM + t]);
            const f32x4* arow = (const f32x4*)(&attn_t[c * 36]);
            #pragma unroll
            for (int q8 = 0; q8 < 8; q8++) {
                f32x4 a4 = arow[q8];
                o[q8 * 4 + 0] += a4[0] * vv;
                o[q8 * 4 + 1] += a4[1] * vv;
                o[q8 * 4 + 2] += a4[2] * vv;
                o[q8 * 4 + 3] += a4[3] * vv;
            }
        }
        #pragma unroll
        for (int q = 0; q < 32; q++)
            aob[(size_t)(base + q) * E_DIM + t] = f2bf(o[q]);
    }
}

// ---------------------------------------------------------------- layernorm (in-place on xf; xf already holds residual sum)
__global__ __launch_bounds__(256)
void ln_k(float* x, const float* __restrict__ g, const float* __restrict__ bta,
          unsigned short* __restrict__ xbo)
{
    __shared__ float red[8];
    const int row = blockIdx.x, t = threadIdx.x;
    const size_t rb = (size_t)row * E_DIM;
    float v[3];
    float s = 0.f, s2 = 0.f;
    #pragma unroll
    for (int i = 0; i < 3; i++) {
        const float a = x[rb + t + i * 256];
        v[i] = a; s += a; s2 += a * a;
    }
    #pragma unroll
    for (int o = 32; o > 0; o >>= 1) { s += __shfl_down(s, o); s2 += __shfl_down(s2, o); }
    const int wv_ = t >> 6;
    if ((t & 63) == 0) { red[wv_] = s; red[4 + wv_] = s2; }
    __syncthreads();
    if (t == 0) {
        red[0] = red[0] + red[1] + red[2] + red[3];
        red[4] = red[4] + red[5] + red[6] + red[7];
    }
    __syncthreads();
    const float mu   = red[0] * (1.f / E_DIM);
    const float var  = red[4] * (1.f / E_DIM) - mu * mu;
    const float rinv = rsqrtf(var + 1e-5f);
    #pragma unroll
    for (int i = 0; i < 3; i++) {
        const int e = t + i * 256;
        const float y = (v[i] - mu) * rinv * g[e] + bta[e];
        x[rb + e] = y;
        xbo[rb + e] = f2bf(y);
    }
}

// ---------------------------------------------------------------- classifier
__global__ __launch_bounds__(256)
void cls_k(const float* __restrict__ xf, const float* __restrict__ Wc,
           const float* __restrict__ bc, float* __restrict__ out)
{
    __shared__ float red[256];
    const int t = threadIdx.x;
    const int o = t >> 2, p = t & 3;      // 64 outputs (b,c), 4 threads each
    const int b = o >> 1, c = o & 1;
    float acc = 0.f;
    for (int e = p; e < E_DIM; e += 4)
        acc += xf[(size_t)b * E_DIM + e] * Wc[e * 2 + c];
    red[t] = acc;
    __syncthreads();
    if (p == 0) out[o] = red[t] + red[t + 1] + red[t + 2] + red[t + 3] + bc[c];
}

// ---------------------------------------------------------------- launch
extern "C" void kernel_launch(void* const* d_in, const int* in_sizes, int n_in,
                              void* d_out, int out_size, void* d_ws, size_t ws_size,
                              hipStream_t stream)
{
    (void)in_sizes; (void)n_in; (void)out_size; (void)ws_size;
    const int*   ids = (const int*)  d_in[0];
    const float* tok = (const float*)d_in[1];
    const float* pos = (const float*)d_in[2];
    const float* Wq  = (const float*)d_in[3];
    const float* bq  = (const float*)d_in[4];
    const float* Wk  = (const float*)d_in[5];
    const float* bk  = (const float*)d_in[6];
    const float* Wv  = (const float*)d_in[7];
    const float* bv  = (const float*)d_in[8];
    const float* Wo  = (const float*)d_in[9];
    const float* bo  = (const float*)d_in[10];
    const float* g1  = (const float*)d_in[11];
    const float* be1 = (const float*)d_in[12];
    const float* g2  = (const float*)d_in[13];
    const float* be2 = (const float*)d_in[14];
    const float* W1  = (const float*)d_in[15];
    const float* bf1 = (const float*)d_in[16];
    const float* W2  = (const float*)d_in[17];
    const float* bf2 = (const float*)d_in[18];
    const float* Wc  = (const float*)d_in[19];
    const float* bc  = (const float*)d_in[20];
    float* out = (float*)d_out;

    // workspace: ~151 MB total
    char* p = (char*)d_ws;
    auto carve = [&](size_t bytes) { char* r = p; p += (bytes + 255) & ~(size_t)255; return r; };
    const size_t NE = (size_t)NTOK * E_DIM;                 // 12.58M elems
    float*          xf = (float*)carve(NE * 4);             // 50.3 MB, residual accumulator
    unsigned short* xb = (unsigned short*)carve(NE * 2);    // 25.2 MB, bf16 shadow of x
    unsigned short* qb = (unsigned short*)carve(NE * 2);    // 25.2 MB  (also ao, also h1 lo)
    unsigned short* kb = (unsigned short*)carve(NE * 2);    // 25.2 MB  (also h1 hi)
    unsigned short* vb = (unsigned short*)carve(NE * 2);    // 25.2 MB
    unsigned short* aob = qb;                               // alias: safe (see attn_k)
    unsigned short* h1c = qb;                               // [NTOK,1536] bf16 overlays q+k

    embed_k<<<NTOK, 256, 0, stream>>>(ids, tok, pos, xf, xb);

    const dim3 gE(NTOK / BM, E_DIM / BN);    // (256, 12)
    const dim3 gH(NTOK / BM, 1536 / BN);     // (256, 24)
    const int FC = 1536;                      // FFN chunk width

    for (int l = 0; l < L_NUM; l++) {
        const float* wq = Wq + (size_t)l * E_DIM * E_DIM;
        const float* wk = Wk + (size_t)l * E_DIM * E_DIM;
        const float* wv = Wv + (size_t)l * E_DIM * E_DIM;
        const float* wo = Wo + (size_t)l * E_DIM * E_DIM;
        const float* w1 = W1 + (size_t)l * E_DIM * F_DIM;
        const float* w2 = W2 + (size_t)l * F_DIM * E_DIM;

        gemm_k<1,0,0><<<gE, 256, 0, stream>>>(xb, wq, bq + l * E_DIM, qb, E_DIM, E_DIM, E_DIM, E_DIM);
        gemm_k<1,0,0><<<gE, 256, 0, stream>>>(xb, wk, bk + l * E_DIM, kb, E_DIM, E_DIM, E_DIM, E_DIM);
        gemm_k<1,0,0><<<gE, 256, 0, stream>>>(xb, wv, bv + l * E_DIM, vb, E_DIM, E_DIM, E_DIM, E_DIM);
        attn_k<<<S_LEN, 1024, 0, stream>>>(qb, kb, vb, aob);
        // xf += ao @ Wo + bo
        gemm_k<0,0,1><<<gE, 256, 0, stream>>>(aob, wo, bo + l * E_DIM, xf, E_DIM, E_DIM, E_DIM, E_DIM);
        ln_k<<<NTOK, 256, 0, stream>>>(xf, g1 + l * E_DIM, be1 + l * E_DIM, xb);
        // FFN in two F/2 chunks: h1c = relu(x@W1[:,c0:] + b1); xf += h1c @ W2[c0:,:] (+b2 once)
        for (int c = 0; c < 2; c++) {
            const int c0 = c * FC;
            gemm_k<1,1,0><<<gH, 256, 0, stream>>>(xb, w1 + c0, bf1 + (size_t)l * F_DIM + c0,
                                                  h1c, E_DIM, F_DIM, FC, E_DIM);
            gemm_k<0,0,1><<<gE, 256, 0, stream>>>(h1c, w2 + (size_t)c0 * E_DIM,
                                                  c == 0 ? (bf2 + l * E_DIM) : (const float*)nullptr,
                                                  xf, FC, E_DIM, E_DIM, FC);
        }
        ln_k<<<NTOK, 256, 0, stream>>>(xf, g2 + l * E_DIM, be2 + l * E_DIM, xb);
    }

    cls_k<<<1, 256, 0, stream>>>(xf, Wc, bc, out);
}

// Round 4
// 2103.045 us; speedup vs baseline: 2.1749x; 2.1749x over previous
//
#include <hip/hip_runtime.h>

// BERT classifier fwd, MI355X. Round 3: m97-structure GEMM (128x128x64 tile,
// global_load_lds staging, pre-transposed bf16 weights, fused QKV, XCD-panel
// swizzle). x kept f32 (xf) + bf16 shadow (xb). Wo/FFN2 accumulate into xf.

#define E_DIM 768
#define F_DIM 3072
#define L_NUM 4
#define S_LEN 512
#define NTOK  (S_LEN * 32)   // 16384
#define QKVN  (3 * E_DIM)    // 2304

typedef float f32x4 __attribute__((ext_vector_type(4)));
typedef unsigned int u32x4 __attribute__((ext_vector_type(4)));
typedef unsigned short u16x4 __attribute__((ext_vector_type(4)));

__device__ __forceinline__ float bf2f(unsigned int bits) {
    return __uint_as_float(bits << 16);
}
__device__ __forceinline__ unsigned short f2bf(float f) {
    unsigned int x = __float_as_uint(f);
    return (unsigned short)((x + 0x7fffu + ((x >> 16) & 1u)) >> 16);
}

#define GLD16(gp, lp) \
    __builtin_amdgcn_global_load_lds( \
        (const __attribute__((address_space(1))) unsigned int*)(gp), \
        (__attribute__((address_space(3))) unsigned int*)(lp), 16, 0, 0)

// ---------------------------------------------------------------- weight transpose+convert
// src [R,C] f32 (layer stride ss) -> dst [C,R] bf16 (layer stride ds)
__global__ __launch_bounds__(256)
void tr_k(const float* __restrict__ src, unsigned short* __restrict__ dst,
          int R, int C, size_t ss, size_t ds)
{
    __shared__ float tile[32][33];
    src += (size_t)blockIdx.z * ss;
    dst += (size_t)blockIdx.z * ds;
    const int r0 = blockIdx.y * 32, c0 = blockIdx.x * 32;
    const int tr = threadIdx.x >> 3, tc = (threadIdx.x & 7) * 4;
    f32x4 v = *(const f32x4*)(src + (size_t)(r0 + tr) * C + c0 + tc);
    tile[tr][tc + 0] = v[0]; tile[tr][tc + 1] = v[1];
    tile[tr][tc + 2] = v[2]; tile[tr][tc + 3] = v[3];
    __syncthreads();
    u16x4 o;
    o[0] = f2bf(tile[tc + 0][tr]); o[1] = f2bf(tile[tc + 1][tr]);
    o[2] = f2bf(tile[tc + 2][tr]); o[3] = f2bf(tile[tc + 3][tr]);
    *(u16x4*)(dst + (size_t)(c0 + tr) * R + r0 + tc) = o;
}

// ---------------------------------------------------------------- qkv bias concat
__global__ __launch_bounds__(256)
void biascat_k(const float* __restrict__ bq, const float* __restrict__ bk,
               const float* __restrict__ bv, float* __restrict__ bqkv)
{
    const int i = blockIdx.x * 256 + threadIdx.x;
    if (i >= L_NUM * QKVN) return;
    const int l = i / QKVN, n = i % QKVN;
    float v;
    if (n < 768)       v = bq[l * 768 + n];
    else if (n < 1536) v = bk[l * 768 + n - 768];
    else               v = bv[l * 768 + n - 1536];
    bqkv[i] = v;
}

// ---------------------------------------------------------------- embedding
__global__ __launch_bounds__(256)
void embed_k(const int* __restrict__ ids, const float* __restrict__ tok,
             const float* __restrict__ pos, float* __restrict__ xf,
             unsigned short* __restrict__ xb)
{
    const int row = blockIdx.x;            // token = s*32 + b
    const int s = row >> 5;
    const int id = ids[row];
    const size_t rb = (size_t)row * E_DIM;
    for (int e = threadIdx.x; e < E_DIM; e += 256) {
        float v = tok[(size_t)id * E_DIM + e] + pos[(size_t)s * E_DIM + e];
        xf[rb + e] = v;
        xb[rb + e] = f2bf(v);
    }
}

// ---------------------------------------------------------------- GEMM (m97 structure)
// C[M,N] = A[M,K](bf16,row) @ BT[N,K](bf16,row)^T + bias
// 128x128x64 tile, 4 waves x (4x4 16x16x32 frags), global_load_lds staging.
// MODE 0: write bf16. MODE 1: write bf16 + relu. MODE 2: accum f32 C += v.
// Swizzle: dispatch d -> i-panel = (d&7)+8*(d/(8*JT)) so one XCD owns a panel.
template<int MODE>
__global__ __launch_bounds__(256)
void gemm2_k(const unsigned short* __restrict__ A, const unsigned short* __restrict__ BT,
             const float* __restrict__ bias, void* __restrict__ Cout,
             int lda, int ldb, int ldc, int K, int JT)
{
    __shared__ unsigned short As[128 * 64];
    __shared__ unsigned short Bs[128 * 64];
    const int t = threadIdx.x;
    const int d = blockIdx.x;
    const int qd = d >> 3, rd = d & 7;
    const int jb = qd % JT;
    const int ib = rd + 8 * (qd / JT);     // M/128 = 128 (div by 8) -> bijective
    const int i0 = ib * 128, j0 = jb * 128;

    const int lane = t & 63, wave = t >> 6;
    const int wm = wave >> 1, wn = wave & 1;
    const int lr = lane & 15, lg = lane >> 4;

    const int sr = t >> 3;          // 0..31 staging row
    const int sc = (t & 7) * 8;     // staging col (8 bf16 = 16B)

    f32x4 acc[4][4];
    #pragma unroll
    for (int mf = 0; mf < 4; mf++)
        #pragma unroll
        for (int nf = 0; nf < 4; nf++) acc[mf][nf] = (f32x4)0.0f;

    const unsigned short* Ab = A  + (size_t)(i0 + sr) * lda + sc;
    const unsigned short* Bb = BT + (size_t)(j0 + sr) * ldb + sc;
    unsigned short* Asp = &As[sr * 64 + sc];
    unsigned short* Bsp = &Bs[sr * 64 + sc];

    for (int k0 = 0; k0 < K; k0 += 64) {
        __syncthreads();   // previous iter's ds_reads complete
        #pragma unroll
        for (int c = 0; c < 4; c++) {
            GLD16(Ab + (size_t)(32 * c) * lda + k0, Asp + 32 * c * 64);
            GLD16(Bb + (size_t)(32 * c) * ldb + k0, Bsp + 32 * c * 64);
        }
        asm volatile("s_waitcnt vmcnt(0)" ::: "memory");
        __syncthreads();
        #pragma unroll
        for (int kk = 0; kk < 64; kk += 32) {
            u32x4 a[4], b[4];
            #pragma unroll
            for (int f = 0; f < 4; f++) {
                a[f] = *(const u32x4*)(&As[(wm * 64 + f * 16 + lr) * 64 + kk + lg * 8]);
                b[f] = *(const u32x4*)(&Bs[(wn * 64 + f * 16 + lr) * 64 + kk + lg * 8]);
            }
            #pragma unroll
            for (int mf = 0; mf < 4; mf++)
                #pragma unroll
                for (int nf = 0; nf < 4; nf++)
                    asm volatile("v_mfma_f32_16x16x32_bf16 %0, %1, %2, %0"
                                 : "+v"(acc[mf][nf]) : "v"(a[mf]), "v"(b[nf]));
        }
    }
    asm volatile("s_nop 7\n\ts_nop 7");   // MFMA D-read hazard insurance
    // epilogue: C/D layout col=lane&15, row=(lane>>4)*4+reg
    #pragma unroll
    for (int nf = 0; nf < 4; nf++) {
        const int col = j0 + wn * 64 + nf * 16 + lr;
        const float bv = bias ? bias[col] : 0.0f;
        #pragma unroll
        for (int mf = 0; mf < 4; mf++) {
            #pragma unroll
            for (int jj = 0; jj < 4; jj++) {
                const int row = i0 + wm * 64 + mf * 16 + lg * 4 + jj;
                const size_t idx = (size_t)row * ldc + col;
                float v = acc[mf][nf][jj] + bv;
                if (MODE == 1) v = fmaxf(v, 0.0f);
                if (MODE == 2) ((float*)Cout)[idx] += v;
                else           ((unsigned short*)Cout)[idx] = f2bf(v);
            }
        }
    }
}

// ---------------------------------------------------------------- attention
// qkv rows: [Q(768) | K(768) | V(768)], stride QKVN. ao overwrites Q cols
// (block-private rows, Q fully consumed before write). Faithful to ref's
// batch-mixing bug: per s, scores [32,32] over batch.
__global__ __launch_bounds__(1024)
void attn_k(unsigned short* __restrict__ qkv)
{
    __shared__ unsigned short Ks[32 * 776];   // +8 pad
    __shared__ float attn_s[32 * 33];
    __shared__ float attn_t[32 * 36];
    const int s = blockIdx.x;
    const int t = threadIdx.x;
    const int base = s * 32;

    for (int ch = t; ch < 32 * 96; ch += 1024) {
        const int r = ch / 96, e = (ch % 96) * 8;
        *(u32x4*)(&Ks[r * 776 + e]) =
            *(const u32x4*)(qkv + (size_t)(base + r) * QKVN + 768 + e);
    }
    __syncthreads();
    {   // scores: thread (q,c)
        const int q = t >> 5, c = t & 31;
        const unsigned short* Qg = qkv + (size_t)(base + q) * QKVN;
        float acc = 0.f;
        for (int e = 0; e < E_DIM; e += 8) {
            u32x4 qv = *(const u32x4*)(Qg + e);
            u32x4 kv = *(const u32x4*)(&Ks[c * 776 + e]);
            #pragma unroll
            for (int w = 0; w < 4; w++) {
                acc += bf2f(qv[w] & 0xffffu) * bf2f(kv[w] & 0xffffu);
                acc += bf2f(qv[w] >> 16)     * bf2f(kv[w] >> 16);
            }
        }
        attn_s[q * 33 + c] = acc * 0.036084391824351615f;  // 1/sqrt(768)
    }
    __syncthreads();
    if (t < 32) {   // softmax row t
        float mx = -1e30f;
        #pragma unroll
        for (int c = 0; c < 32; c++) mx = fmaxf(mx, attn_s[t * 33 + c]);
        float sum = 0.f;
        #pragma unroll
        for (int c = 0; c < 32; c++) sum += expf(attn_s[t * 33 + c] - mx);
        const float r = 1.0f / sum;
        #pragma unroll
        for (int c = 0; c < 32; c++)
            attn_t[c * 36 + t] = expf(attn_s[t * 33 + c] - mx) * r;
    }
    __syncthreads();
    if (t < E_DIM) {   // PV: thread owns output column e=t
        float o[32];
        #pragma unroll
        for (int q = 0; q < 32; q++) o[q] = 0.f;
        for (int c = 0; c < 32; c++) {
            const float vv = bf2f(qkv[(size_t)(base + c) * QKVN + 1536 + t]);
            const f32x4* arow = (const f32x4*)(&attn_t[c * 36]);
            #pragma unroll
            for (int q8 = 0; q8 < 8; q8++) {
                f32x4 a4 = arow[q8];
                o[q8 * 4 + 0] += a4[0] * vv;
                o[q8 * 4 + 1] += a4[1] * vv;
                o[q8 * 4 + 2] += a4[2] * vv;
                o[q8 * 4 + 3] += a4[3] * vv;
            }
        }
        #pragma unroll
        for (int q = 0; q < 32; q++)
            qkv[(size_t)(base + q) * QKVN + t] = f2bf(o[q]);   // ao over Q
    }
}

// ---------------------------------------------------------------- layernorm (in-place on xf)
__global__ __launch_bounds__(256)
void ln_k(float* x, const float* __restrict__ g, const float* __restrict__ bta,
          unsigned short* __restrict__ xbo)
{
    __shared__ float red[8];
    const int row = blockIdx.x, t = threadIdx.x;
    const size_t rb = (size_t)row * E_DIM;
    float v[3];
    float s = 0.f, s2 = 0.f;
    #pragma unroll
    for (int i = 0; i < 3; i++) {
        const float a = x[rb + t + i * 256];
        v[i] = a; s += a; s2 += a * a;
    }
    #pragma unroll
    for (int o = 32; o > 0; o >>= 1) { s += __shfl_down(s, o); s2 += __shfl_down(s2, o); }
    const int wv_ = t >> 6;
    if ((t & 63) == 0) { red[wv_] = s; red[4 + wv_] = s2; }
    __syncthreads();
    if (t == 0) {
        red[0] = red[0] + red[1] + red[2] + red[3];
        red[4] = red[4] + red[5] + red[6] + red[7];
    }
    __syncthreads();
    const float mu   = red[0] * (1.f / E_DIM);
    const float var  = red[4] * (1.f / E_DIM) - mu * mu;
    const float rinv = rsqrtf(var + 1e-5f);
    #pragma unroll
    for (int i = 0; i < 3; i++) {
        const int e = t + i * 256;
        const float y = (v[i] - mu) * rinv * g[e] + bta[e];
        x[rb + e] = y;
        xbo[rb + e] = f2bf(y);
    }
}

// ---------------------------------------------------------------- classifier
__global__ __launch_bounds__(256)
void cls_k(const float* __restrict__ xf, const float* __restrict__ Wc,
           const float* __restrict__ bc, float* __restrict__ out)
{
    __shared__ float red[256];
    const int t = threadIdx.x;
    const int o = t >> 2, p = t & 3;      // 64 outputs (b,c), 4 threads each
    const int b = o >> 1, c = o & 1;
    float acc = 0.f;
    for (int e = p; e < E_DIM; e += 4)
        acc += xf[(size_t)b * E_DIM + e] * Wc[e * 2 + c];
    red[t] = acc;
    __syncthreads();
    if (p == 0) out[o] = red[t] + red[t + 1] + red[t + 2] + red[t + 3] + bc[c];
}

// ---------------------------------------------------------------- launch
extern "C" void kernel_launch(void* const* d_in, const int* in_sizes, int n_in,
                              void* d_out, int out_size, void* d_ws, size_t ws_size,
                              hipStream_t stream)
{
    (void)in_sizes; (void)n_in; (void)out_size; (void)ws_size;
    const int*   ids = (const int*)  d_in[0];
    const float* tok = (const float*)d_in[1];
    const float* pos = (const float*)d_in[2];
    const float* Wq  = (const float*)d_in[3];
    const float* bq  = (const float*)d_in[4];
    const float* Wk  = (const float*)d_in[5];
    const float* bk  = (const float*)d_in[6];
    const float* Wv  = (const float*)d_in[7];
    const float* bv  = (const float*)d_in[8];
    const float* Wo  = (const float*)d_in[9];
    const float* bo  = (const float*)d_in[10];
    const float* g1  = (const float*)d_in[11];
    const float* be1 = (const float*)d_in[12];
    const float* g2  = (const float*)d_in[13];
    const float* be2 = (const float*)d_in[14];
    const float* W1  = (const float*)d_in[15];
    const float* bf1 = (const float*)d_in[16];
    const float* W2  = (const float*)d_in[17];
    const float* bf2 = (const float*)d_in[18];
    const float* Wc  = (const float*)d_in[19];
    const float* bc  = (const float*)d_in[20];
    float* out = (float*)d_out;

    // workspace (~208 MB)
    char* p = (char*)d_ws;
    auto carve = [&](size_t bytes) { char* r = p; p += (bytes + 255) & ~(size_t)255; return r; };
    const size_t NE = (size_t)NTOK * E_DIM;
    float*          xf    = (float*)carve(NE * 4);                        // 50.3 MB
    unsigned short* xb    = (unsigned short*)carve(NE * 2);               // 25.2 MB
    unsigned short* qkv   = (unsigned short*)carve((size_t)NTOK * QKVN * 2); // 75.5 MB
    unsigned short* wqkvT = (unsigned short*)carve((size_t)L_NUM * QKVN * E_DIM * 2); // 14.2 MB
    unsigned short* woT   = (unsigned short*)carve((size_t)L_NUM * E_DIM * E_DIM * 2); // 4.7 MB
    unsigned short* w1T   = (unsigned short*)carve((size_t)L_NUM * F_DIM * E_DIM * 2); // 18.9 MB
    unsigned short* w2T   = (unsigned short*)carve((size_t)L_NUM * E_DIM * F_DIM * 2); // 18.9 MB
    float*          bqkv  = (float*)carve((size_t)L_NUM * QKVN * 4);      // 37 KB
    unsigned short* h1c   = qkv;   // [NTOK,1536] overlays qkv (dead after Wo-GEMM)

    // prologue: transpose+convert weights, concat qkv bias
    const size_t sEE = (size_t)E_DIM * E_DIM, sEF = (size_t)E_DIM * F_DIM;
    tr_k<<<dim3(24, 24, 4), 256, 0, stream>>>(Wq, wqkvT,              768, 768, sEE, (size_t)QKVN * E_DIM);
    tr_k<<<dim3(24, 24, 4), 256, 0, stream>>>(Wk, wqkvT + 768 * 768,  768, 768, sEE, (size_t)QKVN * E_DIM);
    tr_k<<<dim3(24, 24, 4), 256, 0, stream>>>(Wv, wqkvT + 1536 * 768, 768, 768, sEE, (size_t)QKVN * E_DIM);
    tr_k<<<dim3(24, 24, 4), 256, 0, stream>>>(Wo, woT, 768, 768, sEE, sEE);
    tr_k<<<dim3(96, 24, 4), 256, 0, stream>>>(W1, w1T, 768, 3072, sEF, sEF);
    tr_k<<<dim3(24, 96, 4), 256, 0, stream>>>(W2, w2T, 3072, 768, sEF, sEF);
    biascat_k<<<(L_NUM * QKVN + 255) / 256, 256, 0, stream>>>(bq, bk, bv, bqkv);

    embed_k<<<NTOK, 256, 0, stream>>>(ids, tok, pos, xf, xb);

    const int IT = NTOK / 128;   // 128 i-panels
    for (int l = 0; l < L_NUM; l++) {
        const unsigned short* wqkv_l = wqkvT + (size_t)l * QKVN * E_DIM;
        const unsigned short* wo_l   = woT + (size_t)l * sEE;
        const unsigned short* w1_l   = w1T + (size_t)l * sEF;
        const unsigned short* w2_l   = w2T + (size_t)l * sEF;

        // qkv = x @ [Wq|Wk|Wv] + b   (N = 2304)
        gemm2_k<0><<<IT * 18, 256, 0, stream>>>(xb, wqkv_l, bqkv + l * QKVN, qkv,
                                                E_DIM, E_DIM, QKVN, E_DIM, 18);
        attn_k<<<S_LEN, 1024, 0, stream>>>(qkv);
        // xf += ao @ Wo + bo   (ao = qkv cols 0..768, lda 2304)
        gemm2_k<2><<<IT * 6, 256, 0, stream>>>(qkv, wo_l, bo + l * E_DIM, xf,
                                               QKVN, E_DIM, E_DIM, E_DIM, 6);
        ln_k<<<NTOK, 256, 0, stream>>>(xf, g1 + l * E_DIM, be1 + l * E_DIM, xb);
        // FFN in two 1536-wide chunks; h1c overlays qkv
        for (int c = 0; c < 2; c++) {
            const int c0 = c * 1536;
            gemm2_k<1><<<IT * 12, 256, 0, stream>>>(xb, w1_l + (size_t)c0 * E_DIM,
                                                    bf1 + (size_t)l * F_DIM + c0, h1c,
                                                    E_DIM, E_DIM, 1536, E_DIM, 12);
            gemm2_k<2><<<IT * 6, 256, 0, stream>>>(h1c, w2_l + c0,
                                                   c == 0 ? (bf2 + l * E_DIM) : (const float*)nullptr,
                                                   xf, 1536, F_DIM, E_DIM, 1536, 6);
        }
        ln_k<<<NTOK, 256, 0, stream>>>(xf, g2 + l * E_DIM, be2 + l * E_DIM, xb);
    }

    cls_k<<<1, 256, 0, stream>>>(xf, Wc, bc, out);
}

// Round 6
// 1869.608 us; speedup vs baseline: 2.4465x; 1.1249x over previous
//
#include <hip/hip_runtime.h>

// BERT classifier fwd, MI355X. Round 5 == round 4 (never benched: acquisition
// timeout). Keep proven gemm2_k (m97 structure); unchunk FFN (h1 overlays qkv,
// ws_size-checked w/ chunked fallback); MFMA-ized attention score phase.

#define E_DIM 768
#define F_DIM 3072
#define L_NUM 4
#define S_LEN 512
#define NTOK  (S_LEN * 32)   // 16384
#define QKVN  (3 * E_DIM)    // 2304

typedef float f32x4 __attribute__((ext_vector_type(4)));
typedef unsigned int u32x4 __attribute__((ext_vector_type(4)));
typedef unsigned short u16x4 __attribute__((ext_vector_type(4)));

__device__ __forceinline__ float bf2f(unsigned int bits) {
    return __uint_as_float(bits << 16);
}
__device__ __forceinline__ unsigned short f2bf(float f) {
    unsigned int x = __float_as_uint(f);
    return (unsigned short)((x + 0x7fffu + ((x >> 16) & 1u)) >> 16);
}

#define GLD16(gp, lp) \
    __builtin_amdgcn_global_load_lds( \
        (const __attribute__((address_space(1))) unsigned int*)(gp), \
        (__attribute__((address_space(3))) unsigned int*)(lp), 16, 0, 0)

// ---------------------------------------------------------------- weight transpose+convert
// src [R,C] f32 (layer stride ss) -> dst [C,R] bf16 (layer stride ds)
__global__ __launch_bounds__(256)
void tr_k(const float* __restrict__ src, unsigned short* __restrict__ dst,
          int R, int C, size_t ss, size_t ds)
{
    __shared__ float tile[32][33];
    src += (size_t)blockIdx.z * ss;
    dst += (size_t)blockIdx.z * ds;
    const int r0 = blockIdx.y * 32, c0 = blockIdx.x * 32;
    const int tr = threadIdx.x >> 3, tc = (threadIdx.x & 7) * 4;
    f32x4 v = *(const f32x4*)(src + (size_t)(r0 + tr) * C + c0 + tc);
    tile[tr][tc + 0] = v[0]; tile[tr][tc + 1] = v[1];
    tile[tr][tc + 2] = v[2]; tile[tr][tc + 3] = v[3];
    __syncthreads();
    u16x4 o;
    o[0] = f2bf(tile[tc + 0][tr]); o[1] = f2bf(tile[tc + 1][tr]);
    o[2] = f2bf(tile[tc + 2][tr]); o[3] = f2bf(tile[tc + 3][tr]);
    *(u16x4*)(dst + (size_t)(c0 + tr) * R + r0 + tc) = o;
}

// ---------------------------------------------------------------- qkv bias concat
__global__ __launch_bounds__(256)
void biascat_k(const float* __restrict__ bq, const float* __restrict__ bk,
               const float* __restrict__ bv, float* __restrict__ bqkv)
{
    const int i = blockIdx.x * 256 + threadIdx.x;
    if (i >= L_NUM * QKVN) return;
    const int l = i / QKVN, n = i % QKVN;
    float v;
    if (n < 768)       v = bq[l * 768 + n];
    else if (n < 1536) v = bk[l * 768 + n - 768];
    else               v = bv[l * 768 + n - 1536];
    bqkv[i] = v;
}

// ---------------------------------------------------------------- embedding
__global__ __launch_bounds__(256)
void embed_k(const int* __restrict__ ids, const float* __restrict__ tok,
             const float* __restrict__ pos, float* __restrict__ xf,
             unsigned short* __restrict__ xb)
{
    const int row = blockIdx.x;            // token = s*32 + b
    const int s = row >> 5;
    const int id = ids[row];
    const size_t rb = (size_t)row * E_DIM;
    for (int e = threadIdx.x; e < E_DIM; e += 256) {
        float v = tok[(size_t)id * E_DIM + e] + pos[(size_t)s * E_DIM + e];
        xf[rb + e] = v;
        xb[rb + e] = f2bf(v);
    }
}

// ---------------------------------------------------------------- GEMM (m97 structure, proven round 3)
// C[M,N] = A[M,K](bf16,row) @ BT[N,K](bf16,row)^T + bias
// MODE 0: write bf16. MODE 1: write bf16 + relu. MODE 2: accum f32 C += v.
template<int MODE>
__global__ __launch_bounds__(256)
void gemm2_k(const unsigned short* __restrict__ A, const unsigned short* __restrict__ BT,
             const float* __restrict__ bias, void* __restrict__ Cout,
             int lda, int ldb, int ldc, int K, int JT)
{
    __shared__ unsigned short As[128 * 64];
    __shared__ unsigned short Bs[128 * 64];
    const int t = threadIdx.x;
    const int d = blockIdx.x;
    const int qd = d >> 3, rd = d & 7;
    const int jb = qd % JT;
    const int ib = rd + 8 * (qd / JT);
    const int i0 = ib * 128, j0 = jb * 128;

    const int lane = t & 63, wave = t >> 6;
    const int wm = wave >> 1, wn = wave & 1;
    const int lr = lane & 15, lg = lane >> 4;

    const int sr = t >> 3;          // 0..31 staging row
    const int sc = (t & 7) * 8;     // staging col (8 bf16 = 16B)

    f32x4 acc[4][4];
    #pragma unroll
    for (int mf = 0; mf < 4; mf++)
        #pragma unroll
        for (int nf = 0; nf < 4; nf++) acc[mf][nf] = (f32x4)0.0f;

    const unsigned short* Ab = A  + (size_t)(i0 + sr) * lda + sc;
    const unsigned short* Bb = BT + (size_t)(j0 + sr) * ldb + sc;
    unsigned short* Asp = &As[sr * 64 + sc];
    unsigned short* Bsp = &Bs[sr * 64 + sc];

    for (int k0 = 0; k0 < K; k0 += 64) {
        __syncthreads();
        #pragma unroll
        for (int c = 0; c < 4; c++) {
            GLD16(Ab + (size_t)(32 * c) * lda + k0, Asp + 32 * c * 64);
            GLD16(Bb + (size_t)(32 * c) * ldb + k0, Bsp + 32 * c * 64);
        }
        asm volatile("s_waitcnt vmcnt(0)" ::: "memory");
        __syncthreads();
        #pragma unroll
        for (int kk = 0; kk < 64; kk += 32) {
            u32x4 a[4], b[4];
            #pragma unroll
            for (int f = 0; f < 4; f++) {
                a[f] = *(const u32x4*)(&As[(wm * 64 + f * 16 + lr) * 64 + kk + lg * 8]);
                b[f] = *(const u32x4*)(&Bs[(wn * 64 + f * 16 + lr) * 64 + kk + lg * 8]);
            }
            #pragma unroll
            for (int mf = 0; mf < 4; mf++)
                #pragma unroll
                for (int nf = 0; nf < 4; nf++)
                    asm volatile("v_mfma_f32_16x16x32_bf16 %0, %1, %2, %0"
                                 : "+v"(acc[mf][nf]) : "v"(a[mf]), "v"(b[nf]));
        }
    }
    asm volatile("s_nop 7\n\ts_nop 7");
    #pragma unroll
    for (int nf = 0; nf < 4; nf++) {
        const int col = j0 + wn * 64 + nf * 16 + lr;
        const float bv = bias ? bias[col] : 0.0f;
        #pragma unroll
        for (int mf = 0; mf < 4; mf++) {
            #pragma unroll
            for (int jj = 0; jj < 4; jj++) {
                const int row = i0 + wm * 64 + mf * 16 + lg * 4 + jj;
                const size_t idx = (size_t)row * ldc + col;
                float v = acc[mf][nf][jj] + bv;
                if (MODE == 1) v = fmaxf(v, 0.0f);
                if (MODE == 2) ((float*)Cout)[idx] += v;
                else           ((unsigned short*)Cout)[idx] = f2bf(v);
            }
        }
    }
}

// ---------------------------------------------------------------- attention v2
// Per s (faithful batch-mixing bug): wave0 computes scores 32x32 via MFMA
// (frag mappings identical to gemm2_k), in-register softmax via shfl_xor
// over the 16-lane col groups, writes P to attn_t[c][q]. PV: thread owns
// column e. ao overwrites Q cols (Q consumed before barrier).
__global__ __launch_bounds__(768)
void attn_k(unsigned short* __restrict__ qkv)
{
    __shared__ float attn_t[32 * 36];   // [c][q], rows 144B
    const int s = blockIdx.x;
    const int t = threadIdx.x;
    const int base = s * 32;

    if (t < 64) {
        const int lr = t & 15, lg = t >> 4;
        f32x4 sacc[2][2];
        #pragma unroll
        for (int m = 0; m < 2; m++)
            #pragma unroll
            for (int n = 0; n < 2; n++) sacc[m][n] = (f32x4)0.0f;
        const unsigned short* Qb = qkv + (size_t)base * QKVN;
        #pragma unroll 4
        for (int k0 = 0; k0 < E_DIM; k0 += 32) {
            u32x4 a0 = *(const u32x4*)(Qb + (size_t)lr        * QKVN + k0 + lg * 8);
            u32x4 a1 = *(const u32x4*)(Qb + (size_t)(16 + lr) * QKVN + k0 + lg * 8);
            u32x4 b0 = *(const u32x4*)(Qb + (size_t)lr        * QKVN + 768 + k0 + lg * 8);
            u32x4 b1 = *(const u32x4*)(Qb + (size_t)(16 + lr) * QKVN + 768 + k0 + lg * 8);
            asm volatile("v_mfma_f32_16x16x32_bf16 %0, %1, %2, %0" : "+v"(sacc[0][0]) : "v"(a0), "v"(b0));
            asm volatile("v_mfma_f32_16x16x32_bf16 %0, %1, %2, %0" : "+v"(sacc[0][1]) : "v"(a0), "v"(b1));
            asm volatile("v_mfma_f32_16x16x32_bf16 %0, %1, %2, %0" : "+v"(sacc[1][0]) : "v"(a1), "v"(b0));
            asm volatile("v_mfma_f32_16x16x32_bf16 %0, %1, %2, %0" : "+v"(sacc[1][1]) : "v"(a1), "v"(b1));
        }
        asm volatile("s_nop 7\n\ts_nop 7");
        const float scale = 0.036084391824351615f;  // 1/sqrt(768)
        float p[2][2][4];
        #pragma unroll
        for (int m = 0; m < 2; m++) {
            #pragma unroll
            for (int j = 0; j < 4; j++) {
                // row r = m*16 + lg*4 + j; cols spread over n (2) x lr (16)
                float v0 = sacc[m][0][j] * scale;
                float v1 = sacc[m][1][j] * scale;
                float mx = fmaxf(v0, v1);
                #pragma unroll
                for (int o = 1; o < 16; o <<= 1) mx = fmaxf(mx, __shfl_xor(mx, o));
                float e0 = expf(v0 - mx), e1 = expf(v1 - mx);
                float sm = e0 + e1;
                #pragma unroll
                for (int o = 1; o < 16; o <<= 1) sm += __shfl_xor(sm, o);
                const float r = 1.0f / sm;
                p[m][0][j] = e0 * r;
                p[m][1][j] = e1 * r;
            }
        }
        #pragma unroll
        for (int m = 0; m < 2; m++)
            #pragma unroll
            for (int n = 0; n < 2; n++)
                #pragma unroll
                for (int j = 0; j < 4; j++)
                    attn_t[(n * 16 + lr) * 36 + m * 16 + lg * 4 + j] = p[m][n][j];
    }
    __syncthreads();
    if (t < E_DIM) {   // PV: thread owns output column e=t
        float o[32];
        #pragma unroll
        for (int q = 0; q < 32; q++) o[q] = 0.f;
        for (int c = 0; c < 32; c++) {
            const float vv = bf2f(qkv[(size_t)(base + c) * QKVN + 1536 + t]);
            const f32x4* arow = (const f32x4*)(&attn_t[c * 36]);
            #pragma unroll
            for (int q8 = 0; q8 < 8; q8++) {
                f32x4 a4 = arow[q8];
                o[q8 * 4 + 0] += a4[0] * vv;
                o[q8 * 4 + 1] += a4[1] * vv;
                o[q8 * 4 + 2] += a4[2] * vv;
                o[q8 * 4 + 3] += a4[3] * vv;
            }
        }
        #pragma unroll
        for (int q = 0; q < 32; q++)
            qkv[(size_t)(base + q) * QKVN + t] = f2bf(o[q]);   // ao over Q
    }
}

// ---------------------------------------------------------------- layernorm (in-place on xf)
__global__ __launch_bounds__(256)
void ln_k(float* x, const float* __restrict__ g, const float* __restrict__ bta,
          unsigned short* __restrict__ xbo)
{
    __shared__ float red[8];
    const int row = blockIdx.x, t = threadIdx.x;
    const size_t rb = (size_t)row * E_DIM;
    float v[3];
    float s = 0.f, s2 = 0.f;
    #pragma unroll
    for (int i = 0; i < 3; i++) {
        const float a = x[rb + t + i * 256];
        v[i] = a; s += a; s2 += a * a;
    }
    #pragma unroll
    for (int o = 32; o > 0; o >>= 1) { s += __shfl_down(s, o); s2 += __shfl_down(s2, o); }
    const int wv_ = t >> 6;
    if ((t & 63) == 0) { red[wv_] = s; red[4 + wv_] = s2; }
    __syncthreads();
    if (t == 0) {
        red[0] = red[0] + red[1] + red[2] + red[3];
        red[4] = red[4] + red[5] + red[6] + red[7];
    }
    __syncthreads();
    const float mu   = red[0] * (1.f / E_DIM);
    const float var  = red[4] * (1.f / E_DIM) - mu * mu;
    const float rinv = rsqrtf(var + 1e-5f);
    #pragma unroll
    for (int i = 0; i < 3; i++) {
        const int e = t + i * 256;
        const float y = (v[i] - mu) * rinv * g[e] + bta[e];
        x[rb + e] = y;
        xbo[rb + e] = f2bf(y);
    }
}

// ---------------------------------------------------------------- classifier
__global__ __launch_bounds__(256)
void cls_k(const float* __restrict__ xf, const float* __restrict__ Wc,
           const float* __restrict__ bc, float* __restrict__ out)
{
    __shared__ float red[256];
    const int t = threadIdx.x;
    const int o = t >> 2, p = t & 3;
    const int b = o >> 1, c = o & 1;
    float acc = 0.f;
    for (int e = p; e < E_DIM; e += 4)
        acc += xf[(size_t)b * E_DIM + e] * Wc[e * 2 + c];
    red[t] = acc;
    __syncthreads();
    if (p == 0) out[o] = red[t] + red[t + 1] + red[t + 2] + red[t + 3] + bc[c];
}

// ---------------------------------------------------------------- launch
extern "C" void kernel_launch(void* const* d_in, const int* in_sizes, int n_in,
                              void* d_out, int out_size, void* d_ws, size_t ws_size,
                              hipStream_t stream)
{
    (void)in_sizes; (void)n_in; (void)out_size;
    const int*   ids = (const int*)  d_in[0];
    const float* tok = (const float*)d_in[1];
    const float* pos = (const float*)d_in[2];
    const float* Wq  = (const float*)d_in[3];
    const float* bq  = (const float*)d_in[4];
    const float* Wk  = (const float*)d_in[5];
    const float* bk  = (const float*)d_in[6];
    const float* Wv  = (const float*)d_in[7];
    const float* bv  = (const float*)d_in[8];
    const float* Wo  = (const float*)d_in[9];
    const float* bo  = (const float*)d_in[10];
    const float* g1  = (const float*)d_in[11];
    const float* be1 = (const float*)d_in[12];
    const float* g2  = (const float*)d_in[13];
    const float* be2 = (const float*)d_in[14];
    const float* W1  = (const float*)d_in[15];
    const float* bf1 = (const float*)d_in[16];
    const float* W2  = (const float*)d_in[17];
    const float* bf2 = (const float*)d_in[18];
    const float* Wc  = (const float*)d_in[19];
    const float* bc  = (const float*)d_in[20];
    float* out = (float*)d_out;

    auto al = [](size_t b) { return (b + 255) & ~(size_t)255; };
    const size_t NE = (size_t)NTOK * E_DIM;
    const size_t sEE = (size_t)E_DIM * E_DIM, sEF = (size_t)E_DIM * F_DIM;
    const size_t fixed = al(NE * 4) + al(NE * 2)
                       + al((size_t)L_NUM * QKVN * E_DIM * 2) + al((size_t)L_NUM * sEE * 2)
                       + al((size_t)L_NUM * sEF * 2) + al((size_t)L_NUM * sEF * 2)
                       + al((size_t)L_NUM * QKVN * 4);
    const bool big = ws_size >= fixed + al((size_t)NTOK * F_DIM * 2);   // unchunked FFN?

    char* p = (char*)d_ws;
    auto carve = [&](size_t bytes) { char* r = p; p += (bytes + 255) & ~(size_t)255; return r; };
    float*          xf    = (float*)carve(NE * 4);
    unsigned short* xb    = (unsigned short*)carve(NE * 2);
    unsigned short* qkv   = (unsigned short*)carve(big ? (size_t)NTOK * F_DIM * 2
                                                       : (size_t)NTOK * QKVN * 2);
    unsigned short* wqkvT = (unsigned short*)carve((size_t)L_NUM * QKVN * E_DIM * 2);
    unsigned short* woT   = (unsigned short*)carve((size_t)L_NUM * sEE * 2);
    unsigned short* w1T   = (unsigned short*)carve((size_t)L_NUM * sEF * 2);
    unsigned short* w2T   = (unsigned short*)carve((size_t)L_NUM * sEF * 2);
    float*          bqkv  = (float*)carve((size_t)L_NUM * QKVN * 4);
    unsigned short* h1c   = qkv;   // overlays qkv (dead after Wo-GEMM)

    // prologue: transpose+convert weights, concat qkv bias
    tr_k<<<dim3(24, 24, 4), 256, 0, stream>>>(Wq, wqkvT,              768, 768, sEE, (size_t)QKVN * E_DIM);
    tr_k<<<dim3(24, 24, 4), 256, 0, stream>>>(Wk, wqkvT + 768 * 768,  768, 768, sEE, (size_t)QKVN * E_DIM);
    tr_k<<<dim3(24, 24, 4), 256, 0, stream>>>(Wv, wqkvT + 1536 * 768, 768, 768, sEE, (size_t)QKVN * E_DIM);
    tr_k<<<dim3(24, 24, 4), 256, 0, stream>>>(Wo, woT, 768, 768, sEE, sEE);
    tr_k<<<dim3(96, 24, 4), 256, 0, stream>>>(W1, w1T, 768, 3072, sEF, sEF);
    tr_k<<<dim3(24, 96, 4), 256, 0, stream>>>(W2, w2T, 3072, 768, sEF, sEF);
    biascat_k<<<(L_NUM * QKVN + 255) / 256, 256, 0, stream>>>(bq, bk, bv, bqkv);

    embed_k<<<NTOK, 256, 0, stream>>>(ids, tok, pos, xf, xb);

    const int IT = NTOK / 128;   // 128 i-panels
    for (int l = 0; l < L_NUM; l++) {
        const unsigned short* wqkv_l = wqkvT + (size_t)l * QKVN * E_DIM;
        const unsigned short* wo_l   = woT + (size_t)l * sEE;
        const unsigned short* w1_l   = w1T + (size_t)l * sEF;
        const unsigned short* w2_l   = w2T + (size_t)l * sEF;

        gemm2_k<0><<<IT * 18, 256, 0, stream>>>(xb, wqkv_l, bqkv + l * QKVN, qkv,
                                                E_DIM, E_DIM, QKVN, E_DIM, 18);
        attn_k<<<S_LEN, 768, 0, stream>>>(qkv);
        gemm2_k<2><<<IT * 6, 256, 0, stream>>>(qkv, wo_l, bo + l * E_DIM, xf,
                                               QKVN, E_DIM, E_DIM, E_DIM, 6);
        ln_k<<<NTOK, 256, 0, stream>>>(xf, g1 + l * E_DIM, be1 + l * E_DIM, xb);
        if (big) {
            // h1 = relu(x @ W1 + b1)   [16384, 3072]
            gemm2_k<1><<<IT * 24, 256, 0, stream>>>(xb, w1_l, bf1 + (size_t)l * F_DIM, h1c,
                                                    E_DIM, E_DIM, F_DIM, E_DIM, 24);
            // xf += h1 @ W2 + b2
            gemm2_k<2><<<IT * 6, 256, 0, stream>>>(h1c, w2_l, bf2 + l * E_DIM, xf,
                                                   F_DIM, F_DIM, E_DIM, F_DIM, 6);
        } else {
            for (int c = 0; c < 2; c++) {
                const int c0 = c * 1536;
                gemm2_k<1><<<IT * 12, 256, 0, stream>>>(xb, w1_l + (size_t)c0 * E_DIM,
                                                        bf1 + (size_t)l * F_DIM + c0, h1c,
                                                        E_DIM, E_DIM, 1536, E_DIM, 12);
                gemm2_k<2><<<IT * 6, 256, 0, stream>>>(h1c, w2_l + c0,
                                                       c == 0 ? (bf2 + l * E_DIM) : (const float*)nullptr,
                                                       xf, 1536, F_DIM, E_DIM, 1536, 6);
            }
        }
        ln_k<<<NTOK, 256, 0, stream>>>(xf, g2 + l * E_DIM, be2 + l * E_DIM, xb);
    }

    cls_k<<<1, 256, 0, stream>>>(xf, Wc, bc, out);
}